// Round 10
// baseline (254.921 us; speedup 1.0000x reference)
//
#include <hip/hip_runtime.h>
#include <math.h>

// B=4, S=1024, D=768, H=12, E=64, 3D=2304
// Workspace layout (bytes), total ~137 MB:
//   scbuf fp16 scores -> fp16 probs in place : 100,663,296 @ 0   [bh][q][k]
//   qkf  fp16 [4096][1536] (Q,K)  : 12,582,912 @ 100,663,296
//   vbuf fp16 [4096][768]  (V)    :  6,291,456 @ 113,246,208
//   ctx  fp16 [4096][768]         :  6,291,456 @ 119,537,664
//   x_h  fp16 :  6,291,456 @ 125,829,120
//   wq_h fp16 :  3,538,944 @ 132,120,576
//   wp_h fp16 :  1,179,648 @ 135,659,520

typedef _Float16 f16;
typedef __attribute__((ext_vector_type(8))) _Float16 f16x8;
typedef __attribute__((ext_vector_type(2))) _Float16 f16x2;
typedef __attribute__((ext_vector_type(4))) float f32x4;
typedef __attribute__((ext_vector_type(2))) float f32x2;
typedef unsigned short u16;

__device__ __forceinline__ u16 f2h(float f) {      // RTN convert
  f16 h = (f16)f;
  return __builtin_bit_cast(u16, h);
}
__device__ __forceinline__ unsigned pk2h(float a, float b) {
  return __builtin_bit_cast(unsigned, __builtin_amdgcn_cvt_pkrtz(a, b));
}

__device__ __forceinline__ void async16(const void* g, void* l) {
  __builtin_amdgcn_global_load_lds(
      (const __attribute__((address_space(1))) unsigned int*)g,
      (__attribute__((address_space(3))) unsigned int*)l, 16, 0, 0);
}

#define MFMA_F16(a, b, c) __builtin_amdgcn_mfma_f32_16x16x32_f16((a), (b), (c), 0, 0, 0)

// ---------------- prep: cast x, Wqkv, Wp to fp16 ----------------
__global__ __launch_bounds__(256) void k_prep(const float* __restrict__ x,
                                              const float* __restrict__ Wqkv,
                                              const float* __restrict__ Wp,
                                              u16* __restrict__ xh,
                                              u16* __restrict__ wh,
                                              u16* __restrict__ wph) {
  const int blk = blockIdx.x, t = threadIdx.x;
  if (blk < 3072) {
    int i = blk * 256 + t;
    float4 v = ((const float4*)x)[i];
    ((ushort4*)xh)[i] = make_ushort4(f2h(v.x), f2h(v.y), f2h(v.z), f2h(v.w));
  } else if (blk < 4800) {
    int i = (blk - 3072) * 256 + t;
    float4 v = ((const float4*)Wqkv)[i];
    ((ushort4*)wh)[i] = make_ushort4(f2h(v.x), f2h(v.y), f2h(v.z), f2h(v.w));
  } else {
    int i = (blk - 4800) * 256 + t;
    float4 v = ((const float4*)Wp)[i];
    ((ushort4*)wph)[i] = make_ushort4(f2h(v.x), f2h(v.y), f2h(v.z), f2h(v.w));
  }
}

// ---------------- K1: qkv = x @ Wqkv^T, fp16 single-MFMA ----------------
__global__ __launch_bounds__(256) void k_qkv(const u16* __restrict__ Axh,
                                             const u16* __restrict__ Bwh,
                                             u16* __restrict__ qkf,
                                             u16* __restrict__ vbuf) {
  __shared__ u16 smem[16384];
  u16* As = smem;
  u16* Bs = smem + 4096;
  const int t = threadIdx.x, lane = t & 63, wave = t >> 6;
  const int wm = wave >> 1, wn = wave & 1;
  const int quad = lane >> 4, l16 = lane & 15;
  const int pid = blockIdx.x;
  const int group = pid / 144;
  const int rem = pid - group * 144;
  const int m0 = (group * 8 + (rem & 7)) * 128;
  const int n0 = (rem >> 3) * 128;
  const bool vblk = (n0 >= 1536);
  const int srow = t >> 2, sch = (t & 3) * 8;
  f32x4 acc[4][4];
#pragma unroll
  for (int i = 0; i < 4; ++i)
#pragma unroll
    for (int j = 0; j < 4; ++j) acc[i][j] = (f32x4){0.f, 0.f, 0.f, 0.f};
  for (int k0 = 0; k0 < 768; k0 += 32) {
    const size_t ga = (size_t)(m0 + srow) * 768 + k0 + sch;
    const size_t gb = (size_t)(n0 + srow) * 768 + k0 + sch;
    __syncthreads();
    async16(Axh + ga, &As[t * 8]);
    async16(Axh + ga + (size_t)64 * 768, &As[2048 + t * 8]);
    async16(Bwh + gb, &Bs[t * 8]);
    async16(Bwh + gb + (size_t)64 * 768, &Bs[2048 + t * 8]);
    __syncthreads();
    f16x8 af[4], bfr[4];
#pragma unroll
    for (int i = 0; i < 4; ++i) af[i] = *(const f16x8*)&As[(wm * 64 + i * 16 + l16) * 32 + quad * 8];
#pragma unroll
    for (int j = 0; j < 4; ++j) bfr[j] = *(const f16x8*)&Bs[(wn * 64 + j * 16 + l16) * 32 + quad * 8];
#pragma unroll
    for (int i = 0; i < 4; ++i)
#pragma unroll
      for (int j = 0; j < 4; ++j) acc[i][j] = MFMA_F16(af[i], bfr[j], acc[i][j]);
  }
  __syncthreads();
  u16* T = smem;
#pragma unroll
  for (int i = 0; i < 4; ++i)
#pragma unroll
    for (int j = 0; j < 4; ++j)
#pragma unroll
      for (int r = 0; r < 4; ++r) {
        const int row = wm * 64 + i * 16 + quad * 4 + r;
        const int col = wn * 64 + j * 16 + l16;
        T[row * 128 + (col ^ ((row & 7) << 4))] = f2h(acc[i][j][r]);
      }
  __syncthreads();
  const int row = t >> 1, halfc = (t & 1) * 64;
  const int sw = (row & 7) << 4;
  u16* dst = vblk ? (vbuf + (size_t)(m0 + row) * 768 + (n0 - 1536) + halfc)
                  : (qkf + (size_t)(m0 + row) * 1536 + n0 + halfc);
#pragma unroll
  for (int c = 0; c < 64; c += 8)
    *(uint4*)(dst + c) = *(const uint4*)&T[row * 128 + ((halfc + c) ^ sw)];
}

// ---------------- K2: scores(fp16) = Q @ K^T per (b,h), single fp16 MFMA ----------------
__global__ __launch_bounds__(256) void k_qk(const u16* __restrict__ qkf,
                                            u16* __restrict__ scbuf) {
  __shared__ u16 smem[4][4096];
  u16* As = smem[0]; u16* Bs = smem[1];
  const int t = threadIdx.x, lane = t & 63, wave = t >> 6;
  const int wm = wave >> 1, wn = wave & 1;
  const int quad = lane >> 4, l16 = lane & 15;
  const int bh = blockIdx.z, b = bh / 12, h = bh % 12;
  const int m0 = blockIdx.y * 128, n0 = blockIdx.x * 128;
  const int srow = t >> 2, sch = (t & 3) * 8;
  u16* C = scbuf + ((size_t)bh << 20);
  f32x4 acc[4][4];
#pragma unroll
  for (int i = 0; i < 4; ++i)
#pragma unroll
    for (int j = 0; j < 4; ++j) acc[i][j] = (f32x4){0.f, 0.f, 0.f, 0.f};
  for (int k0 = 0; k0 < 64; k0 += 32) {
    const size_t ga = (size_t)(b * 1024 + m0 + srow) * 1536 + h * 64 + k0 + sch;
    const size_t gb = (size_t)(b * 1024 + n0 + srow) * 1536 + 768 + h * 64 + k0 + sch;
    __syncthreads();
    async16(qkf + ga, &As[t * 8]);
    async16(qkf + ga + (size_t)64 * 1536, &As[2048 + t * 8]);
    async16(qkf + gb, &Bs[t * 8]);
    async16(qkf + gb + (size_t)64 * 1536, &Bs[2048 + t * 8]);
    __syncthreads();
    f16x8 af[4], bfr[4];
#pragma unroll
    for (int i = 0; i < 4; ++i) af[i] = *(const f16x8*)&As[(wm * 64 + i * 16 + l16) * 32 + quad * 8];
#pragma unroll
    for (int j = 0; j < 4; ++j) bfr[j] = *(const f16x8*)&Bs[(wn * 64 + j * 16 + l16) * 32 + quad * 8];
#pragma unroll
    for (int i = 0; i < 4; ++i)
#pragma unroll
      for (int j = 0; j < 4; ++j) acc[i][j] = MFMA_F16(af[i], bfr[j], acc[i][j]);
  }
  __syncthreads();
  u16* T = &smem[0][0];
#pragma unroll
  for (int i = 0; i < 4; ++i)
#pragma unroll
    for (int j = 0; j < 4; ++j)
#pragma unroll
      for (int r = 0; r < 4; ++r) {
        const int row = wm * 64 + i * 16 + quad * 4 + r;
        const int col = wn * 64 + j * 16 + l16;
        T[row * 128 + (col ^ ((row & 7) << 4))] = f2h(acc[i][j][r]);
      }
  __syncthreads();
  const int row = t >> 1, halfc = (t & 1) * 64;
  const int sw = (row & 7) << 4;
  u16* dst = C + (size_t)(m0 + row) * 1024 + n0 + halfc;
#pragma unroll
  for (int c = 0; c < 64; c += 8)
    *(uint4*)(dst + c) = *(const uint4*)&T[row * 128 + ((halfc + c) ^ sw)];
}

// ---------------- K3: mix1 -> const-shift softmax -> mix2, MFMA-based ----------------
// One block per (b,q). Scores X[12 h][1024 k] staged as h-pair planes X1[8][1024] dw.
// mix1: C1[kpos][g] = X[kpos][h] . Wl[g][h]  via 16x16x32 f16 MFMA (one per 16-kpos tile)
// E kept in FP32 regs until normalized (unnormalized exp can reach ~e^28, overflows fp16).
__global__ __launch_bounds__(256) void k_mix(u16* __restrict__ scbuf,
                                             const float* __restrict__ Wl,
                                             const float* __restrict__ bl,
                                             const float* __restrict__ Ww,
                                             const float* __restrict__ bw) {
  __shared__ unsigned X1[8 * 1024];        // 32 KB; plane p=h/2, dw per kpos = h_even | h_odd<<16
  __shared__ u16 wlB[16 * 32];             // B-frag layout [g][h], zero-padded
  __shared__ u16 wwB[16 * 32];
  __shared__ float biases[32];             // [0..15]=bl-16, [16..31]=bw
  __shared__ float sums_l[4][16];
  __shared__ unsigned scratch[4][8 * 20];  // per-wave transpose: 8 g-pair rows x 20 dw
  u16* outb = (u16*)X1;                    // alias after pass A: 12 rows x 1028 u16

  const int t = threadIdx.x, lane = t & 63, wave = t >> 6;
  const int quad = lane >> 4, l16 = lane & 15;
  const int bq = blockIdx.x, b = bq >> 10, q = bq & 1023;

  for (int idx = t; idx < 512; idx += 256) {
    int r = idx >> 5, c = idx & 31;
    wlB[idx] = (r < 12 && c < 12) ? f2h(Wl[r * 12 + c]) : (u16)0;
    wwB[idx] = (r < 12 && c < 12) ? f2h(Ww[r * 12 + c]) : (u16)0;
  }
  if (t < 16) biases[t] = (t < 12) ? bl[t] - 16.f : -16.f;
  if (t < 16) biases[16 + t] = (t < 12) ? bw[t] : 0.f;
  {
    uint4 z = {0u, 0u, 0u, 0u};
    *(uint4*)&X1[6 * 1024 + t * 4] = z;   // planes 6,7 = h 12..15 -> zero
    *(uint4*)&X1[7 * 1024 + t * 4] = z;
  }
  // fill planes 0..5: 12 uint2 loads (kpos 4t..4t+3 per h), interleave h-pairs
  const size_t base = ((size_t)(b * 12) << 20) + ((size_t)q << 10) + 4 * t;
  uint2 hv[12];
#pragma unroll
  for (int h = 0; h < 12; ++h)
    hv[h] = *(const uint2*)(scbuf + base + ((size_t)h << 20));
#pragma unroll
  for (int p = 0; p < 6; ++p) {
    uint2 a = hv[2 * p], bb = hv[2 * p + 1];
    uint4 w4;
    w4.x = (a.x & 0xffffu) | (bb.x << 16);
    w4.y = (a.x >> 16) | (bb.x & 0xffff0000u);
    w4.z = (a.y & 0xffffu) | (bb.y << 16);
    w4.w = (a.y >> 16) | (bb.y & 0xffff0000u);
    *(uint4*)&X1[p * 1024 + 4 * t] = w4;
  }
  __syncthreads();

  f16x8 wl_f = *(const f16x8*)&wlB[l16 * 32 + quad * 8];
  f16x8 ww_f = *(const f16x8*)&wwB[l16 * 32 + quad * 8];
  const float mybl = biases[l16];
  const float mybw = biases[16 + l16];

  // PASS A: mix1 MFMA + exp(l-16); E kept in FP32 regs; accumulate per-g sums
  float Ereg[16][4];
  float s = 0.f;
#pragma unroll
  for (int nt = 0; nt < 16; ++nt) {
    const int kb = wave * 256 + nt * 16;
    uint4 av;
    if (quad < 2) {
      av.x = X1[(quad * 4 + 0) * 1024 + kb + l16];
      av.y = X1[(quad * 4 + 1) * 1024 + kb + l16];
      av.z = X1[(quad * 4 + 2) * 1024 + kb + l16];
      av.w = X1[(quad * 4 + 3) * 1024 + kb + l16];
    } else {
      av.x = av.y = av.z = av.w = 0u;
    }
    f16x8 a1 = __builtin_bit_cast(f16x8, av);
    f32x4 c = (f32x4){0.f, 0.f, 0.f, 0.f};
    c = MFMA_F16(a1, wl_f, c);
    float e0 = __expf(c[0] + mybl), e1 = __expf(c[1] + mybl);
    float e2 = __expf(c[2] + mybl), e3 = __expf(c[3] + mybl);
    s += (e0 + e1) + (e2 + e3);
    Ereg[nt][0] = e0; Ereg[nt][1] = e1; Ereg[nt][2] = e2; Ereg[nt][3] = e3;
  }
  s += __shfl_xor(s, 16);
  s += __shfl_xor(s, 32);
  if (lane < 16) sums_l[wave][l16] = s;
  __syncthreads();   // sums ready; X1 pass-A reads done -> outb alias safe
  const float inv = 1.0f / (sums_l[0][l16] + sums_l[1][l16] + sums_l[2][l16] + sums_l[3][l16]);

  // PASS B: normalize (fp32) -> wave-local transpose -> mix2 MFMA -> outb
  unsigned* scr = scratch[wave];
#pragma unroll
  for (int nt = 0; nt < 16; ++nt) {
    float v0 = Ereg[nt][0] * inv, v1 = Ereg[nt][1] * inv;
    float v2 = Ereg[nt][2] * inv, v3 = Ereg[nt][3] * inv;
    float p0 = __shfl_xor(v0, 1), p1 = __shfl_xor(v1, 1);
    float p2 = __shfl_xor(v2, 1), p3 = __shfl_xor(v3, 1);
    if (!(l16 & 1)) {
      uint4 w4;
      w4.x = pk2h(v0, p0); w4.y = pk2h(v1, p1);
      w4.z = pk2h(v2, p2); w4.w = pk2h(v3, p3);
      *(uint4*)&scr[(l16 >> 1) * 20 + quad * 4] = w4;
    }
    uint4 av2;
    if (quad < 2) {
      av2.x = scr[(quad * 4 + 0) * 20 + l16];
      av2.y = scr[(quad * 4 + 1) * 20 + l16];
      av2.z = scr[(quad * 4 + 2) * 20 + l16];
      av2.w = scr[(quad * 4 + 3) * 20 + l16];
    } else {
      av2.x = av2.y = av2.z = av2.w = 0u;
    }
    f16x8 a2 = __builtin_bit_cast(f16x8, av2);
    f32x4 c2 = (f32x4){0.f, 0.f, 0.f, 0.f};
    c2 = MFMA_F16(a2, ww_f, c2);
    if (l16 < 12) {
      const int kb = wave * 256 + nt * 16 + quad * 4;
      *(unsigned*)&outb[l16 * 1028 + kb] = pk2h(c2[0] + mybw, c2[1] + mybw);
      *(unsigned*)&outb[l16 * 1028 + kb + 2] = pk2h(c2[2] + mybw, c2[3] + mybw);
    }
  }
  __syncthreads();
#pragma unroll
  for (int g = 0; g < 12; ++g) {
    uint2 v = *(const uint2*)&outb[g * 1028 + 4 * t];
    *(uint2*)(scbuf + base + ((size_t)g << 20)) = v;
  }
}

// ---------------- K4: ctx = P(fp16) @ V(fp16) per (b,h); V transposed in-LDS ----------------
__global__ __launch_bounds__(256) void k_pv(const u16* __restrict__ probs,
                                            const u16* __restrict__ vbuf,
                                            u16* __restrict__ ctx) {
  __shared__ u16 As[4096];
  __shared__ u16 Bs[64 * 40];
  const int t = threadIdx.x, lane = t & 63, wave = t >> 6;
  const int wm = wave >> 1, wn = wave & 1;
  const int quad = lane >> 4, l16 = lane & 15;
  const int bh = blockIdx.y, b = bh / 12, h = bh % 12;
  const int m0 = blockIdx.x * 128;
  const u16* P = probs + ((size_t)bh << 20);
  const int srow = t >> 2, sch = (t & 3) * 8;
  const int ev = t & 63, s8 = (t >> 6) * 8;
  f32x4 acc[4][2];
#pragma unroll
  for (int i = 0; i < 4; ++i)
#pragma unroll
    for (int j = 0; j < 2; ++j) acc[i][j] = (f32x4){0.f, 0.f, 0.f, 0.f};
  for (int k0 = 0; k0 < 1024; k0 += 32) {
    const u16* vp = vbuf + (size_t)(b * 1024 + k0 + s8) * 768 + h * 64 + ev;
    u16 vcol[8];
#pragma unroll
    for (int i = 0; i < 8; ++i) vcol[i] = vp[(size_t)i * 768];
    __syncthreads();
    const u16* ga = P + (size_t)(m0 + srow) * 1024 + k0 + sch;
    async16(ga, &As[t * 8]);
    async16(ga + (size_t)64 * 1024, &As[2048 + t * 8]);
    *(ushort4*)&Bs[ev * 40 + s8] = make_ushort4(vcol[0], vcol[1], vcol[2], vcol[3]);
    *(ushort4*)&Bs[ev * 40 + s8 + 4] = make_ushort4(vcol[4], vcol[5], vcol[6], vcol[7]);
    __syncthreads();
    f16x8 af[4], bfr[2];
#pragma unroll
    for (int i = 0; i < 4; ++i) af[i] = *(const f16x8*)&As[(wm * 64 + i * 16 + l16) * 32 + quad * 8];
#pragma unroll
    for (int j = 0; j < 2; ++j) bfr[j] = *(const f16x8*)&Bs[(wn * 32 + j * 16 + l16) * 40 + quad * 8];
#pragma unroll
    for (int i = 0; i < 4; ++i)
#pragma unroll
      for (int j = 0; j < 2; ++j) acc[i][j] = MFMA_F16(af[i], bfr[j], acc[i][j]);
  }
#pragma unroll
  for (int i = 0; i < 4; ++i)
#pragma unroll
    for (int j = 0; j < 2; ++j)
#pragma unroll
      for (int r = 0; r < 4; ++r) {
        int q = m0 + wm * 64 + i * 16 + quad * 4 + r;
        int e = wn * 32 + j * 16 + l16;
        ctx[(size_t)(b * 1024 + q) * 768 + h * 64 + e] = f2h(acc[i][j][r]);
      }
}

// ---------------- K5: out = ctx @ Wp^T + bp (fp16 MFMA, fp32 out) ----------------
__global__ __launch_bounds__(256) void k_oproj(const u16* __restrict__ A,
                                               const u16* __restrict__ Bm,
                                               const float* __restrict__ bp,
                                               float* __restrict__ out) {
  __shared__ u16 As[4096];
  __shared__ u16 Bs[4096];
  const int t = threadIdx.x, lane = t & 63, wave = t >> 6;
  const int wm = wave >> 1, wn = wave & 1;
  const int quad = lane >> 4, l16 = lane & 15;
  const int m0 = blockIdx.y * 128, n0 = blockIdx.x * 128;
  const int srow = t >> 2, sch = (t & 3) * 8;
  f32x4 acc[4][4];
#pragma unroll
  for (int i = 0; i < 4; ++i)
#pragma unroll
    for (int j = 0; j < 4; ++j) acc[i][j] = (f32x4){0.f, 0.f, 0.f, 0.f};
  for (int k0 = 0; k0 < 768; k0 += 32) {
    __syncthreads();
    const u16* ga = A + (size_t)(m0 + srow) * 768 + k0 + sch;
    const u16* gb = Bm + (size_t)(n0 + srow) * 768 + k0 + sch;
    async16(ga, &As[t * 8]);
    async16(ga + (size_t)64 * 768, &As[2048 + t * 8]);
    async16(gb, &Bs[t * 8]);
    async16(gb + (size_t)64 * 768, &Bs[2048 + t * 8]);
    __syncthreads();
    f16x8 af[4], bfr[4];
#pragma unroll
    for (int i = 0; i < 4; ++i) af[i] = *(const f16x8*)&As[(wm * 64 + i * 16 + l16) * 32 + quad * 8];
#pragma unroll
    for (int j = 0; j < 4; ++j) bfr[j] = *(const f16x8*)&Bs[(wn * 64 + j * 16 + l16) * 32 + quad * 8];
#pragma unroll
    for (int i = 0; i < 4; ++i)
#pragma unroll
      for (int j = 0; j < 4; ++j) acc[i][j] = MFMA_F16(af[i], bfr[j], acc[i][j]);
  }
#pragma unroll
  for (int i = 0; i < 4; ++i)
#pragma unroll
    for (int j = 0; j < 4; ++j)
#pragma unroll
      for (int r = 0; r < 4; ++r) {
        const int row = m0 + wm * 64 + i * 16 + quad * 4 + r;
        const int col = n0 + wn * 64 + j * 16 + l16;
        out[(size_t)row * 768 + col] = acc[i][j][r] + bp[col];
      }
}

extern "C" void kernel_launch(void* const* d_in, const int* in_sizes, int n_in,
                              void* d_out, int out_size, void* d_ws, size_t ws_size,
                              hipStream_t stream) {
  const float* x    = (const float*)d_in[0];
  const float* Wqkv = (const float*)d_in[1];
  const float* Wl   = (const float*)d_in[2];
  const float* bl   = (const float*)d_in[3];
  const float* Ww   = (const float*)d_in[4];
  const float* bw   = (const float*)d_in[5];
  const float* Wp   = (const float*)d_in[6];
  const float* bp   = (const float*)d_in[7];
  float* out = (float*)d_out;

  char* ws = (char*)d_ws;
  u16* scbuf = (u16*)(ws + 0);               // 100,663,296 B
  u16* qkf   = (u16*)(ws + 100663296ull);    //  12,582,912 B
  u16* vbuf  = (u16*)(ws + 113246208ull);    //   6,291,456 B
  u16* ctx   = (u16*)(ws + 119537664ull);    //   6,291,456 B
  u16* x_h   = (u16*)(ws + 125829120ull);    //   6,291,456 B
  u16* wq_h  = (u16*)(ws + 132120576ull);    //   3,538,944 B
  u16* wp_h  = (u16*)(ws + 135659520ull);    //   1,179,648 B

  hipLaunchKernelGGL(k_prep, dim3(5376), dim3(256), 0, stream,
                     x, Wqkv, Wp, x_h, wq_h, wp_h);
  hipLaunchKernelGGL(k_qkv,  dim3(576),      dim3(256), 0, stream, x_h, wq_h, qkf, vbuf);
  hipLaunchKernelGGL(k_qk,   dim3(8, 8, 48), dim3(256), 0, stream, qkf, scbuf);
  hipLaunchKernelGGL(k_mix,  dim3(4096),     dim3(256), 0, stream, scbuf, Wl, bl, Ww, bw);
  hipLaunchKernelGGL(k_pv,   dim3(8, 48),    dim3(256), 0, stream, scbuf, vbuf, ctx);
  hipLaunchKernelGGL(k_oproj, dim3(6, 32),   dim3(256), 0, stream, ctx, wp_h, bp, out);
}